// Round 12
// baseline (336.264 us; speedup 1.0000x reference)
//
#include <hip/hip_runtime.h>

// RNN-T loss forward: B=8, T=128, U=100, V=1024, BLANK=0.
// INSTRUMENTATION ROUND 2: lse_kernel launched 3x (idempotent staging writes)
// + dp_kernel 4x (as round 8). Pins L via 2L = total - r8_total - ~4us.
// Kernels byte-identical to rounds 7/8 for anchor comparability.

#define NEGV (-1e30f)

constexpr int Bb = 8;
constexpr int Tt = 128;
constexpr int Uu = 100;
constexpr int Vv = 1024;
constexpr int UP1 = Uu + 1;
constexpr int DROWS = 244;       // staging rows (d up to 232 + lane spill)
constexpr int DPAD  = 104;       // staging row pitch in floats
constexpr int CHUNK = 8;         // diagonals per chunk
constexpr int LPITCH = 128;      // LDS row pitch in floats

__device__ __forceinline__ float laddexp(float x, float y) {
    float m = fmaxf(x, y);
    float d = fabsf(x - y);
    return m + __logf(1.0f + __expf(-d));
}

// lane l receives lane l-1's value; lane 0 -> 0
__device__ __forceinline__ float wave_shr1(float x) {
    return __builtin_bit_cast(float, __builtin_amdgcn_update_dpp(
        0, __builtin_bit_cast(int, x), 0x138, 0xf, 0xf, true));
}

__device__ __forceinline__ float readlane_f(float x, int lane) {
    return __builtin_bit_cast(float,
        __builtin_amdgcn_readlane(__builtin_bit_cast(int, x), lane));
}

// Kernel 1: per (b,t,u) row of V=1024 logits compute lse; scatter the two
// needed log-probs into diagonal-major staging.
__global__ __launch_bounds__(256) void lse_kernel(
        const float* __restrict__ logits,
        const int*   __restrict__ targets,
        float* __restrict__ bS,
        float* __restrict__ eS) {
    const int wid  = blockIdx.x * 4 + (threadIdx.x >> 6);   // row index
    const int lane = threadIdx.x & 63;
    const int b   = wid / (Tt * UP1);
    const int rem = wid - b * (Tt * UP1);
    const int t   = rem / UP1;
    const int u   = rem - t * UP1;

    const float* row = logits + (size_t)wid * Vv;
    const float4* r4 = (const float4*)row;
    float4 x0 = r4[lane];
    float4 x1 = r4[lane + 64];
    float4 x2 = r4[lane + 128];
    float4 x3 = r4[lane + 192];

    float m = fmaxf(fmaxf(fmaxf(x0.x, x0.y), fmaxf(x0.z, x0.w)),
                    fmaxf(fmaxf(x1.x, x1.y), fmaxf(x1.z, x1.w)));
    m = fmaxf(m, fmaxf(fmaxf(fmaxf(x2.x, x2.y), fmaxf(x2.z, x2.w)),
                       fmaxf(fmaxf(x3.x, x3.y), fmaxf(x3.z, x3.w))));
    #pragma unroll
    for (int d = 32; d > 0; d >>= 1) m = fmaxf(m, __shfl_xor(m, d, 64));

    float s = __expf(x0.x - m) + __expf(x0.y - m) + __expf(x0.z - m) + __expf(x0.w - m)
            + __expf(x1.x - m) + __expf(x1.y - m) + __expf(x1.z - m) + __expf(x1.w - m)
            + __expf(x2.x - m) + __expf(x2.y - m) + __expf(x2.z - m) + __expf(x2.w - m)
            + __expf(x3.x - m) + __expf(x3.y - m) + __expf(x3.z - m) + __expf(x3.w - m);
    #pragma unroll
    for (int d = 32; d > 0; d >>= 1) s += __shfl_xor(s, d, 64);

    float lse = m + __logf(s);

    if (lane == 0) {
        const int dw = t + u + 1;                       // 1..228
        bS[((size_t)b * DROWS + dw) * DPAD + u] = x0.x - lse;   // row[0] = BLANK
        if (u < Uu) {
            int tgt = targets[b * Uu + u];
            eS[((size_t)b * DROWS + dw) * DPAD + (u + 1)] = row[tgt] - lse;
        }
    }
}

// Kernel 2: one 128-thread block per batch. Wave 0 = DP consumer (from LDS),
// wave 1 = producer (global -> LDS double-buffer, 2 register sets deep).
__global__ __launch_bounds__(128) void dp_kernel(
        const float* __restrict__ bS,
        const float* __restrict__ eS,
        const int*   __restrict__ logit_lengths,
        const int*   __restrict__ target_lengths,
        float* __restrict__ nll) {
    const int b    = blockIdx.x;
    const int tid  = threadIdx.x;
    const int wv   = tid >> 6;          // 0 = consumer, 1 = producer
    const int lane = tid & 63;
    const float* bB = bS + (size_t)b * DROWS * DPAD;
    const float* eB = eS + (size_t)b * DROWS * DPAD;
    const int tl = logit_lengths[b];
    const int ul = target_lengths[b];
    const int t_idx = tl - 2;           // reference reads alpha[tl-2][ul]
    const int dcap  = t_idx + ul;       // diagonal of the readout cell

    __shared__ float ringB[2][CHUNK][LPITCH];
    __shared__ float ringE[2][CHUNK][LPITCH];

    // consumer state
    const int u0 = lane * 2, u1 = u0 + 1;
    float aP0 = (lane == 0) ? 0.0f : NEGV;   // alpha diag 0: only (0,0)=0
    float aP1 = NEGV;
    float cap = (dcap == 0) ? 0.0f : NEGV;

    // producer state: two register sets (chunk k lives in set k&1)
    float2 LAb[CHUNK], LAe[CHUNK], LBb[CHUNK], LBe[CHUNK];

#define PLOAD(SETb, SETe, ck) do {                                           \
        const float* _pb = bB + (size_t)((ck) * CHUNK + 1) * DPAD + lane * 2;\
        const float* _pe = eB + (size_t)((ck) * CHUNK + 1) * DPAD + lane * 2;\
        _Pragma("unroll")                                                    \
        for (int r = 0; r < CHUNK; ++r) {                                    \
            SETb[r] = *(const float2*)(_pb + r * DPAD);                      \
            SETe[r] = *(const float2*)(_pe + r * DPAD);                      \
        }                                                                    \
    } while (0)

#define PWRITE(SETb, SETe, slot) do {                                        \
        _Pragma("unroll")                                                    \
        for (int r = 0; r < CHUNK; ++r) {                                    \
            *(float2*)&ringB[slot][r][lane * 2] = SETb[r];                   \
            *(float2*)&ringE[slot][r][lane * 2] = SETe[r];                   \
        }                                                                    \
    } while (0)

    // consumer: process chunk cc from LDS slot; diagonals cc*8+1 .. cc*8+8
#define CCHUNK(cc, slot) do {                                                \
        float2 Bv[CHUNK], Ev[CHUNK];                                         \
        _Pragma("unroll")                                                    \
        for (int r = 0; r < CHUNK; ++r) {                                    \
            Bv[r] = *(const float2*)&ringB[slot][r][u0];                     \
            Ev[r] = *(const float2*)&ringE[slot][r][u0];                     \
        }                                                                    \
        _Pragma("unroll")                                                    \
        for (int r = 0; r < CHUNK; ++r) {                                    \
            const int dv = (cc) * CHUNK + 1 + r;                             \
            float sh  = wave_shr1(aP1);                                      \
            float t1b = (u1 < dv) ? aP1 + Bv[r].y : NEGV;                    \
            float t1e = aP0 + Ev[r].y;                                       \
            float t0b = (u0 < dv) ? aP0 + Bv[r].x : NEGV;                    \
            float t0e = (lane >= 1) ? sh + Ev[r].x : NEGV;                   \
            float n1 = laddexp(t1b, t1e);                                    \
            float n0 = laddexp(t0b, t0e);                                    \
            aP0 = n0; aP1 = n1;                                              \
            if (dv == dcap) {                                                \
                float w0 = readlane_f(n0, ul >> 1);                          \
                float w1 = readlane_f(n1, ul >> 1);                          \
                cap = (ul & 1) ? w1 : w0;                                    \
            }                                                                \
        }                                                                    \
    } while (0)

    // prologue: producer loads chunks 0,1 and writes chunk 0 to slot 0
    if (wv == 1) {
        PLOAD(LAb, LAe, 0);
        PLOAD(LBb, LBe, 1);
        PWRITE(LAb, LAe, 0);
    }
    __syncthreads();

    // main: 14 x (even half, odd half); consumer handles chunks 0..27
    for (int c2 = 0; c2 < 14; ++c2) {
        const int c = c2 * 2;
        if (wv == 1) {
            PLOAD(LAb, LAe, c + 2);
            PWRITE(LBb, LBe, 1);
        } else {
            CCHUNK(c, 0);
        }
        __syncthreads();
        if (wv == 1) {
            if (c2 < 13) PLOAD(LBb, LBe, c + 3);
            PWRITE(LAb, LAe, 0);
        } else {
            CCHUNK(c + 1, 1);
        }
        __syncthreads();
    }
    // final chunk 28 (slot 0), consumer only
    if (wv == 0) {
        CCHUNK(28, 0);
        if (lane == 0) {
            float ll = cap + bB[(size_t)(dcap + 1) * DPAD + ul]; // + blank[t_idx][ul]
            nll[b] = -ll;
        }
    }
#undef PLOAD
#undef PWRITE
#undef CCHUNK
}

__global__ void mean_kernel(const float* __restrict__ nll, float* __restrict__ out) {
    if (threadIdx.x == 0 && blockIdx.x == 0) {
        float s = 0.0f;
        for (int i = 0; i < Bb; ++i) s += nll[i];
        out[0] = s / (float)Bb;
    }
}

extern "C" void kernel_launch(void* const* d_in, const int* in_sizes, int n_in,
                              void* d_out, int out_size, void* d_ws, size_t ws_size,
                              hipStream_t stream) {
    const float* logits         = (const float*)d_in[0];
    const int*   targets        = (const int*)d_in[1];
    const int*   logit_lengths  = (const int*)d_in[2];
    const int*   target_lengths = (const int*)d_in[3];
    float* out = (float*)d_out;

    float* ws   = (float*)d_ws;
    float* bS   = ws;                                   // 8*244*104 floats
    float* eS   = bS + (size_t)Bb * DROWS * DPAD;
    float* nll  = eS + (size_t)Bb * DROWS * DPAD;       // 8 floats (real)
    float* nllX = nll + 8;                              // 8 floats (dummy)

    const int rows = Bb * Tt * UP1;                     // 103424, divisible by 4
    // lse x3: idempotent staging writes; pins L = (total - r8_total - ~4)/2
    lse_kernel<<<rows / 4, 256, 0, stream>>>(logits, targets, bS, eS);
    lse_kernel<<<rows / 4, 256, 0, stream>>>(logits, targets, bS, eS);
    lse_kernel<<<rows / 4, 256, 0, stream>>>(logits, targets, bS, eS);
    // dp x4: #1 real, #2-4 timing probes (as round 8)
    dp_kernel<<<Bb, 128, 0, stream>>>(bS, eS, logit_lengths, target_lengths, nll);
    dp_kernel<<<Bb, 128, 0, stream>>>(bS, eS, logit_lengths, target_lengths, nllX);
    dp_kernel<<<Bb, 128, 0, stream>>>(bS, eS, logit_lengths, target_lengths, nllX);
    dp_kernel<<<Bb, 128, 0, stream>>>(bS, eS, logit_lengths, target_lengths, nllX);
    mean_kernel<<<1, 64, 0, stream>>>(nll, out);
}

// Round 13
// 92.731 us; speedup vs baseline: 3.6263x; 3.6263x over previous
//
#include <hip/hip_runtime.h>

// RNN-T loss forward: B=8, T=128, U=100, V=1024, BLANK=0.
// out = mean_b of -( alpha[tl-2, ul] + blank_lp[tl-2, ul] )
//
// lse_kernel (HBM-floor bound, 424 MB read): log-softmax over V; stage the
//   two needed PROBABILITIES (not log-probs) as bf16 into diagonal-major
//   staging. Prob domain turns the DP into pure FMA.
// dp_kernel: one block (9 waves) per batch. Waves 1..8 bulk-copy staging
//   region (29 diagonals) global->LDS + zero pads, release LDS flag; wave 0
//   runs the 232-step chain as FMA with wave-max rescale every <=8 steps:
//   P[u] = P_prev[u]*B[u] + P_prev[u-1]*E[u],  S += log(max) at rescales.

constexpr int Bb = 8;
constexpr int Tt = 128;
constexpr int Uu = 100;
constexpr int Vv = 1024;
constexpr int UP1 = Uu + 1;
constexpr int DROWS = 244;       // global staging rows per batch
constexpr int DPAD  = 104;       // staging row pitch (bf16 elems)
constexpr int LROWS = 233;       // LDS rows d = 0..232
constexpr int REG   = 29;        // diagonals per copy region
constexpr int NREG  = 8;         // 8 * 29 = 232 diagonals

// ---- bf16 helpers (manual, RNE) ------------------------------------------
__device__ __forceinline__ unsigned short f2bf(float f) {
    unsigned int u = __builtin_bit_cast(unsigned int, f);
    u += 0x7fffu + ((u >> 16) & 1u);
    return (unsigned short)(u >> 16);
}
__device__ __forceinline__ float bflo(unsigned int p) {   // low bf16 -> f32
    return __builtin_bit_cast(float, p << 16);
}
__device__ __forceinline__ float bfhi(unsigned int p) {   // high bf16 -> f32
    return __builtin_bit_cast(float, p & 0xffff0000u);
}

// lane l receives lane l-1's value; lane 0 -> 0  (prob-domain identity!)
__device__ __forceinline__ float wave_shr1(float x) {
    return __builtin_bit_cast(float, __builtin_amdgcn_update_dpp(
        0, __builtin_bit_cast(int, x), 0x138, 0xf, 0xf, true));
}

__device__ __forceinline__ float readlane_f(float x, int lane) {
    return __builtin_bit_cast(float,
        __builtin_amdgcn_readlane(__builtin_bit_cast(int, x), lane));
}

// inclusive max-scan over 64 lanes via DPP (lane 63 = global max)
#define DPP_MAXSTEP(x, ctrl, rmask) {                                        \
    float _t = __builtin_bit_cast(float, __builtin_amdgcn_update_dpp(        \
        __builtin_bit_cast(int, x), __builtin_bit_cast(int, x),              \
        ctrl, rmask, 0xf, false));                                           \
    x = fmaxf(x, _t); }
#define WAVE_SCAN_MAX(x)           \
    DPP_MAXSTEP(x, 0x111, 0xf);    \
    DPP_MAXSTEP(x, 0x112, 0xf);    \
    DPP_MAXSTEP(x, 0x114, 0xf);    \
    DPP_MAXSTEP(x, 0x118, 0xf);    \
    DPP_MAXSTEP(x, 0x142, 0xa);    \
    DPP_MAXSTEP(x, 0x143, 0xc)

// Kernel 1: per (b,t,u) row of V=1024 logits compute lse; stage bf16 PROBS:
//   bS[b][d][u]   = exp(blank_lp[t][u]) at d = t+u+1
//   eS[b][d][u+1] = exp(emit_lp [t][u]) at d = t+u+1
__global__ __launch_bounds__(256) void lse_kernel(
        const float* __restrict__ logits,
        const int*   __restrict__ targets,
        unsigned short* __restrict__ bS,
        unsigned short* __restrict__ eS) {
    const int wid  = blockIdx.x * 4 + (threadIdx.x >> 6);   // row index
    const int lane = threadIdx.x & 63;
    const int b   = wid / (Tt * UP1);
    const int rem = wid - b * (Tt * UP1);
    const int t   = rem / UP1;
    const int u   = rem - t * UP1;

    const float* row = logits + (size_t)wid * Vv;
    const float4* r4 = (const float4*)row;
    float4 x0 = r4[lane];
    float4 x1 = r4[lane + 64];
    float4 x2 = r4[lane + 128];
    float4 x3 = r4[lane + 192];

    float m = fmaxf(fmaxf(fmaxf(x0.x, x0.y), fmaxf(x0.z, x0.w)),
                    fmaxf(fmaxf(x1.x, x1.y), fmaxf(x1.z, x1.w)));
    m = fmaxf(m, fmaxf(fmaxf(fmaxf(x2.x, x2.y), fmaxf(x2.z, x2.w)),
                       fmaxf(fmaxf(x3.x, x3.y), fmaxf(x3.z, x3.w))));
    #pragma unroll
    for (int d = 32; d > 0; d >>= 1) m = fmaxf(m, __shfl_xor(m, d, 64));

    float s = __expf(x0.x - m) + __expf(x0.y - m) + __expf(x0.z - m) + __expf(x0.w - m)
            + __expf(x1.x - m) + __expf(x1.y - m) + __expf(x1.z - m) + __expf(x1.w - m)
            + __expf(x2.x - m) + __expf(x2.y - m) + __expf(x2.z - m) + __expf(x2.w - m)
            + __expf(x3.x - m) + __expf(x3.y - m) + __expf(x3.z - m) + __expf(x3.w - m);
    #pragma unroll
    for (int d = 32; d > 0; d >>= 1) s += __shfl_xor(s, d, 64);

    float lse = m + __logf(s);

    if (lane == 0) {
        const int dw = t + u + 1;                       // 1..228
        bS[((size_t)b * DROWS + dw) * DPAD + u] = f2bf(__expf(x0.x - lse));
        if (u < Uu) {
            int tgt = targets[b * Uu + u];
            eS[((size_t)b * DROWS + dw) * DPAD + (u + 1)] = f2bf(__expf(row[tgt] - lse));
        }
    }
}

// Kernel 2: one 576-thread block (9 waves) per batch element.
__global__ __launch_bounds__(576) void dp_kernel(
        const unsigned short* __restrict__ bS,
        const unsigned short* __restrict__ eS,
        const int* __restrict__ logit_lengths,
        const int* __restrict__ target_lengths,
        float* __restrict__ nll) {
    const int b    = blockIdx.x;
    const int tid  = threadIdx.x;
    const int wvi  = tid >> 6;          // 0 = consumer, 1..8 = copy waves
    const int lane = tid & 63;

    __shared__ __align__(16) unsigned short lB[LROWS][DPAD];
    __shared__ __align__(16) unsigned short lE[LROWS][DPAD];
    __shared__ int sflag[NREG];

    if (tid < NREG) sflag[tid] = 0;
    __syncthreads();

    const size_t bstride = (size_t)DROWS * DPAD;

    if (wvi >= 1) {
        // -------- copy wave: region w = rows [1+29w .. 29+29w], both arrays
        const int w = wvi - 1;
        const int row0 = 1 + REG * w;
        constexpr int RBYTES = REG * DPAD * 2;          // 6032 bytes
        const char* gb = (const char*)(bS + (size_t)b * bstride + (size_t)row0 * DPAD);
        const char* ge = (const char*)(eS + (size_t)b * bstride + (size_t)row0 * DPAD);
        char* db = (char*)&lB[row0][0];
        char* de = (char*)&lE[row0][0];
        for (int k = lane * 16; k < RBYTES; k += 64 * 16) {
            *(uint4*)(db + k) = *(const uint4*)(gb + k);
            *(uint4*)(de + k) = *(const uint4*)(ge + k);
        }
        // zero the never-staged pad slots (cols 101..103, eS col 0)
        if (lane < REG) {
            const int d = row0 + lane;
            lB[d][101] = 0; lB[d][102] = 0; lB[d][103] = 0;
            lE[d][0] = 0; lE[d][101] = 0; lE[d][102] = 0; lE[d][103] = 0;
        }
        __hip_atomic_store(&sflag[w], 1, __ATOMIC_RELEASE,
                           __HIP_MEMORY_SCOPE_WORKGROUP);
        return;
    }

    // -------- consumer wave: 232-step FMA chain with block rescaling -------
    const int tl = logit_lengths[b];
    const int ul = target_lengths[b];
    const int t_idx = tl - 2;           // reference reads alpha[tl-2][ul]
    const int dcap  = t_idx + ul;       // diagonal of the readout cell

    const int u0 = lane * 2;

    float P0 = (lane == 0) ? 1.0f : 0.0f;   // exp(alpha) on diag 0
    float P1 = 0.0f;
    float S  = 0.0f;                         // accumulated log-scale
    float capP = (dcap == 0) ? 1.0f : 0.0f;
    float capS = 0.0f;

#define STEP(dv, ub, ue) do {                                          \
        float Bx = bflo(ub), By = bfhi(ub);                            \
        float Ex = bflo(ue), Ey = bfhi(ue);                            \
        float sh = wave_shr1(P1);                                      \
        float n1 = fmaf(P1, By, P0 * Ey);                              \
        float n0 = fmaf(P0, Bx, sh * Ex);                              \
        P0 = n0; P1 = n1;                                              \
        if ((dv) == dcap) {                                            \
            float w0 = readlane_f(n0, ul >> 1);                        \
            float w1 = readlane_f(n1, ul >> 1);                        \
            capP = (ul & 1) ? w1 : w0;                                 \
            capS = S;                                                  \
        }                                                              \
    } while (0)

#define RESCALE do {                                                   \
        float gm = fmaxf(P0, P1);                                      \
        WAVE_SCAN_MAX(gm);                                             \
        float mm = readlane_f(gm, 63);                                 \
        float rr = 1.0f / mm;                                          \
        P0 *= rr; P1 *= rr;                                            \
        S += __logf(mm);                                               \
    } while (0)

#define GROUP(N, JOFF) do {                                            \
        unsigned int ub[N], ue[N];                                     \
        _Pragma("unroll")                                              \
        for (int r = 0; r < (N); ++r) {                                \
            ub[r] = *(const unsigned int*)&lB[dbase + (JOFF) + r][u0]; \
            ue[r] = *(const unsigned int*)&lE[dbase + (JOFF) + r][u0]; \
        }                                                              \
        _Pragma("unroll")                                              \
        for (int r = 0; r < (N); ++r)                                  \
            STEP(dbase + (JOFF) + r, ub[r], ue[r]);                    \
        RESCALE;                                                       \
    } while (0)

    for (int w = 0; w < NREG; ++w) {
        while (__hip_atomic_load(&sflag[w], __ATOMIC_ACQUIRE,
                                 __HIP_MEMORY_SCOPE_WORKGROUP) == 0)
            __builtin_amdgcn_s_sleep(1);
        __builtin_amdgcn_sched_barrier(0);

        const int dbase = 1 + REG * w;
        GROUP(8, 0); GROUP(8, 8); GROUP(8, 16); GROUP(5, 24);
    }
#undef GROUP
#undef RESCALE
#undef STEP

    if (lane == 0) {
        // final blank term: prob at diagonal row dcap+1 (<= 227), slot ul
        unsigned short hv = lB[dcap + 1][ul];
        float blk = __builtin_bit_cast(float, ((unsigned int)hv) << 16);
        nll[b] = -(__logf(capP) + capS + __logf(blk));
    }
}

__global__ void mean_kernel(const float* __restrict__ nll, float* __restrict__ out) {
    if (threadIdx.x == 0 && blockIdx.x == 0) {
        float s = 0.0f;
        for (int i = 0; i < Bb; ++i) s += nll[i];
        out[0] = s / (float)Bb;
    }
}

extern "C" void kernel_launch(void* const* d_in, const int* in_sizes, int n_in,
                              void* d_out, int out_size, void* d_ws, size_t ws_size,
                              hipStream_t stream) {
    const float* logits         = (const float*)d_in[0];
    const int*   targets        = (const int*)d_in[1];
    const int*   logit_lengths  = (const int*)d_in[2];
    const int*   target_lengths = (const int*)d_in[3];
    float* out = (float*)d_out;

    unsigned short* bS = (unsigned short*)d_ws;          // 8*244*104 bf16
    unsigned short* eS = bS + (size_t)Bb * DROWS * DPAD;
    float* nll = (float*)(eS + (size_t)Bb * DROWS * DPAD);   // 8 floats

    const int rows = Bb * Tt * UP1;                      // 103424, divisible by 4
    lse_kernel<<<rows / 4, 256, 0, stream>>>(logits, targets, bS, eS);
    dp_kernel<<<Bb, 576, 0, stream>>>(bS, eS, logit_lengths, target_lengths, nll);
    mean_kernel<<<1, 64, 0, stream>>>(nll, out);
}